// Round 1
// baseline (288.005 us; speedup 1.0000x reference)
//
#include <hip/hip_runtime.h>

#define D  64   // feature dim (fixed by problem)
#define JB 256  // columns (x2 rows) per block = 4 waves * 64 lanes
#define IB 256  // x1 rows per block

// Each lane caches one x2 row (64 fp32) in VGPRs. x1 row is wave-uniform ->
// scalar loads (SGPR operand is free in VALU). 2 VALU inst per (i,j,k):
// v_sub_f32 + v_add_f32 with abs() modifier. 4 accumulators break the
// dependent-add chain.
__global__ __launch_bounds__(256, 4) void laplace_l1_kernel(
    const float* __restrict__ x1, const float* __restrict__ x2,
    float* __restrict__ out, int n, int m)
{
    const int j     = blockIdx.x * JB + threadIdx.x;   // output column / x2 row
    const int ibase = blockIdx.y * IB;

    // Cache this lane's x2 row in registers (fully static indexing).
    float b[D];
    const float4* x2r = reinterpret_cast<const float4*>(x2 + (size_t)j * D);
#pragma unroll
    for (int q = 0; q < D / 4; ++q) {
        float4 v = x2r[q];
        b[4*q+0] = v.x; b[4*q+1] = v.y; b[4*q+2] = v.z; b[4*q+3] = v.w;
    }

    for (int i = ibase; i < ibase + IB; ++i) {
        const float4* a4 = reinterpret_cast<const float4*>(x1 + (size_t)i * D);
        float acc0 = 0.f, acc1 = 0.f, acc2 = 0.f, acc3 = 0.f;
#pragma unroll
        for (int q = 0; q < D / 4; ++q) {
            float4 av = a4[q];   // wave-uniform -> s_load_dwordx4
            acc0 += fabsf(av.x - b[4*q+0]);
            acc1 += fabsf(av.y - b[4*q+1]);
            acc2 += fabsf(av.z - b[4*q+2]);
            acc3 += fabsf(av.w - b[4*q+3]);
        }
        float s = (acc0 + acc1) + (acc2 + acc3);
        // dist = s/64; clamp_min(1e-15) is a no-op in fp32 (exp(-1e-15)==1.0f).
        out[(size_t)i * m + j] = __expf(s * -0.015625f);
    }
}

extern "C" void kernel_launch(void* const* d_in, const int* in_sizes, int n_in,
                              void* d_out, int out_size, void* d_ws, size_t ws_size,
                              hipStream_t stream)
{
    const float* x1 = (const float*)d_in[0];
    const float* x2 = (const float*)d_in[1];
    float* out = (float*)d_out;
    const int n = in_sizes[0] / D;   // 8192
    const int m = in_sizes[1] / D;   // 8192

    dim3 grid(m / JB, n / IB);       // 32 x 32 = 1024 blocks
    laplace_l1_kernel<<<grid, 256, 0, stream>>>(x1, x2, out, n, m);
}

// Round 2
// 205.320 us; speedup vs baseline: 1.4027x; 1.4027x over previous
//
#include <hip/hip_runtime.h>

#define D  64    // feature dim (fixed by problem)
#define JB 256   // columns (x2 rows) per block = 4 waves * 64 lanes
#define IB 64    // x1 rows per block (fp16 kernel)

typedef _Float16 h2 __attribute__((ext_vector_type(2)));

// ---- pre-kernel: convert x1,x2 fp32 -> fp16 (RTN) into workspace ----
__global__ void cvt_f32_to_f16(const float* __restrict__ x1,
                               const float* __restrict__ x2,
                               _Float16* __restrict__ x1h,
                               _Float16* __restrict__ x2h,
                               int n1, int n2)  // float counts
{
    int idx = blockIdx.x * blockDim.x + threadIdx.x;  // one idx = 4 floats
    int t1 = n1 / 4, tt = (n1 + n2) / 4;
    if (idx < t1) {
        float4 v = reinterpret_cast<const float4*>(x1)[idx];
        h2 lo = { (_Float16)v.x, (_Float16)v.y };
        h2 hi = { (_Float16)v.z, (_Float16)v.w };
        uint2 u = { __builtin_bit_cast(unsigned, lo), __builtin_bit_cast(unsigned, hi) };
        reinterpret_cast<uint2*>(x1h)[idx] = u;
    } else if (idx < tt) {
        int k = idx - t1;
        float4 v = reinterpret_cast<const float4*>(x2)[k];
        h2 lo = { (_Float16)v.x, (_Float16)v.y };
        h2 hi = { (_Float16)v.z, (_Float16)v.w };
        uint2 u = { __builtin_bit_cast(unsigned, lo), __builtin_bit_cast(unsigned, hi) };
        reinterpret_cast<uint2*>(x2h)[k] = u;
    }
}

// ---- main kernel: packed-fp16 L1 distance, fp32 accumulation via v_dot2 ----
// Per 2 dims: v_pk_add_f16 (sub, neg mod) + v_and_b32 (abs) + v_dot2_f32_f16
// = 1.5 VALU inst/dim. x2 row pinned in 32 VGPRs; x1 row wave-uniform.
__global__ __launch_bounds__(256, 6) void laplace_f16_kernel(
    const _Float16* __restrict__ x1h, const _Float16* __restrict__ x2h,
    float* __restrict__ out, int n, int m)
{
    const int j     = blockIdx.x * JB + threadIdx.x;
    const int ibase = blockIdx.y * IB;

    // Cache this lane's x2 row as 32 packed half2 words.
    unsigned bb[32];
    const uint4* b4 = reinterpret_cast<const uint4*>(x2h + (size_t)j * D);
#pragma unroll
    for (int c = 0; c < 8; ++c) {
        uint4 v = b4[c];
        bb[4*c+0] = v.x; bb[4*c+1] = v.y; bb[4*c+2] = v.z; bb[4*c+3] = v.w;
    }
    // Pin in VGPRs: opaque redefinition stops the compiler from re-loading
    // these inside the i-loop (round-1 failure mode).
#pragma unroll
    for (int q = 0; q < 32; ++q) asm volatile("" : "+v"(bb[q]));

    const h2 one2 = { (_Float16)1.0f, (_Float16)1.0f };

    for (int i = ibase; i < ibase + IB; ++i) {
        const uint4* a4 = reinterpret_cast<const uint4*>(x1h + (size_t)i * D);
        float acc0 = 0.f, acc1 = 0.f, acc2 = 0.f, acc3 = 0.f;
#pragma unroll
        for (int c = 0; c < 8; ++c) {
            uint4 av = a4[c];   // wave-uniform -> scalar load
            {
                h2 t = __builtin_bit_cast(h2, av.x) - __builtin_bit_cast(h2, bb[4*c+0]);
                t = __builtin_bit_cast(h2, __builtin_bit_cast(unsigned, t) & 0x7FFF7FFFu);
                acc0 = __builtin_amdgcn_fdot2(t, one2, acc0, false);
            }
            {
                h2 t = __builtin_bit_cast(h2, av.y) - __builtin_bit_cast(h2, bb[4*c+1]);
                t = __builtin_bit_cast(h2, __builtin_bit_cast(unsigned, t) & 0x7FFF7FFFu);
                acc1 = __builtin_amdgcn_fdot2(t, one2, acc1, false);
            }
            {
                h2 t = __builtin_bit_cast(h2, av.z) - __builtin_bit_cast(h2, bb[4*c+2]);
                t = __builtin_bit_cast(h2, __builtin_bit_cast(unsigned, t) & 0x7FFF7FFFu);
                acc2 = __builtin_amdgcn_fdot2(t, one2, acc2, false);
            }
            {
                h2 t = __builtin_bit_cast(h2, av.w) - __builtin_bit_cast(h2, bb[4*c+3]);
                t = __builtin_bit_cast(h2, __builtin_bit_cast(unsigned, t) & 0x7FFF7FFFu);
                acc3 = __builtin_amdgcn_fdot2(t, one2, acc3, false);
            }
        }
        float s = (acc0 + acc1) + (acc2 + acc3);
        // dist = s/64; clamp_min(1e-15) is a no-op in fp32.
        out[(size_t)i * m + j] = __expf(s * -0.015625f);
    }
}

// ---- fallback (ws too small): round-1 fp32 kernel with pinned b ----
__global__ __launch_bounds__(256, 4) void laplace_f32_kernel(
    const float* __restrict__ x1, const float* __restrict__ x2,
    float* __restrict__ out, int n, int m)
{
    const int j     = blockIdx.x * JB + threadIdx.x;
    const int ibase = blockIdx.y * 256;

    float b[D];
    const float4* x2r = reinterpret_cast<const float4*>(x2 + (size_t)j * D);
#pragma unroll
    for (int q = 0; q < D / 4; ++q) {
        float4 v = x2r[q];
        b[4*q+0] = v.x; b[4*q+1] = v.y; b[4*q+2] = v.z; b[4*q+3] = v.w;
    }
#pragma unroll
    for (int q = 0; q < D; ++q) asm volatile("" : "+v"(b[q]));

    for (int i = ibase; i < ibase + 256; ++i) {
        const float4* a4 = reinterpret_cast<const float4*>(x1 + (size_t)i * D);
        float acc0 = 0.f, acc1 = 0.f, acc2 = 0.f, acc3 = 0.f;
#pragma unroll
        for (int q = 0; q < D / 4; ++q) {
            float4 av = a4[q];
            acc0 += fabsf(av.x - b[4*q+0]);
            acc1 += fabsf(av.y - b[4*q+1]);
            acc2 += fabsf(av.z - b[4*q+2]);
            acc3 += fabsf(av.w - b[4*q+3]);
        }
        float s = (acc0 + acc1) + (acc2 + acc3);
        out[(size_t)i * m + j] = __expf(s * -0.015625f);
    }
}

extern "C" void kernel_launch(void* const* d_in, const int* in_sizes, int n_in,
                              void* d_out, int out_size, void* d_ws, size_t ws_size,
                              hipStream_t stream)
{
    const float* x1 = (const float*)d_in[0];
    const float* x2 = (const float*)d_in[1];
    float* out = (float*)d_out;
    const int n = in_sizes[0] / D;   // 8192
    const int m = in_sizes[1] / D;   // 8192

    const size_t need = ((size_t)n + (size_t)m) * D * sizeof(_Float16);  // 2 MB
    if (ws_size >= need) {
        _Float16* x1h = (_Float16*)d_ws;
        _Float16* x2h = x1h + (size_t)n * D;
        const int total4 = (in_sizes[0] + in_sizes[1]) / 4;
        cvt_f32_to_f16<<<(total4 + 255) / 256, 256, 0, stream>>>(
            x1, x2, x1h, x2h, in_sizes[0], in_sizes[1]);
        dim3 grid(m / JB, n / IB);   // 32 x 128
        laplace_f16_kernel<<<grid, 256, 0, stream>>>(x1h, x2h, out, n, m);
    } else {
        dim3 grid(m / JB, n / 256); // 32 x 32
        laplace_f32_kernel<<<grid, 256, 0, stream>>>(x1, x2, out, n, m);
    }
}